// Round 3
// baseline (1682.817 us; speedup 1.0000x reference)
//
#include <hip/hip_runtime.h>
#include <hip/hip_bf16.h>
#include <stdint.h>

#define THRESH 1.5f
constexpr int BB = 8, HH = 1024, WW = 1024;
constexpr int NPIX = BB * HH * WW;   // 8388608 = 2^23
constexpr int HW   = HH * WW;        // 1048576

// ---------------------------------------------------------------------------
// parent[] encoding:
//   value < NPIX  : union-find pointer (value == self <=> unclaimed root)
//   value >= NPIX : claimed root; compact id = value - NPIX
// ---------------------------------------------------------------------------
__device__ __forceinline__ int find_root(const int* __restrict__ P, int x) {
    int p = P[x];
    while (p != x && p < NPIX) { x = p; p = P[x]; }
    return x;
}

__device__ __forceinline__ void merge(int* P, int a, int b) {
    int ra = find_root(P, a);
    int rb = find_root(P, b);
    while (ra != rb) {
        if (ra < rb) { int t = ra; ra = rb; rb = t; }   // ra > rb
        int old = atomicCAS(&P[ra], ra, rb);            // link larger -> smaller
        if (old == ra) break;
        ra = find_root(P, old);
        rb = find_root(P, rb);
    }
}

// Pass 1: init parent + stats arrays (ws poisoned 0xAA every launch)
__global__ void init_k(int* __restrict__ parent, int* __restrict__ cnt,
                       unsigned long long* __restrict__ best,
                       int* __restrict__ counter, int cap) {
    int i = blockIdx.x * blockDim.x + threadIdx.x;
    if (i < NPIX) parent[i] = i;
    if (i < cap)  { cnt[i] = 0; best[i] = 0ull; }
    if (i == 0)   *counter = 0;
}

// Pass 2: union each fg pixel with W, NW, N, NE fg neighbors (covers every
// 8-adjacency edge exactly once; r>0 keeps us inside one image).
__global__ void union_k(const float* __restrict__ x, int* __restrict__ parent) {
    int i = blockIdx.x * blockDim.x + threadIdx.x;
    if (i >= NPIX) return;
    if (!(x[i] >= THRESH)) return;
    int c = i & (WW - 1);
    int r = (i & (HW - 1)) >> 10;
    if (c > 0 && x[i - 1] >= THRESH) merge(parent, i, i - 1);
    if (r > 0) {
        if (x[i - WW] >= THRESH) merge(parent, i, i - WW);
        if (c > 0      && x[i - WW - 1] >= THRESH) merge(parent, i, i - WW - 1);
        if (c < WW - 1 && x[i - WW + 1] >= THRESH) merge(parent, i, i - WW + 1);
    }
}

// Pass 3: full path-compress every fg pixel; roots claim dense compact ids.
__global__ void claim_k(const float* __restrict__ x, int* __restrict__ parent,
                        int* __restrict__ counter) {
    int i = blockIdx.x * blockDim.x + threadIdx.x;
    if (i >= NPIX) return;
    if (!(x[i] >= THRESH)) return;
    int r = find_root(parent, i);
    if (r == i) parent[i] = NPIX + atomicAdd(counter, 1);
    else        parent[i] = r;
}

__device__ __forceinline__ int compact_id(const int* __restrict__ P, int i) {
    int e = P[i];                      // direct root ptr or own claim
    if (e < NPIX) e = P[e];            // root's claim (>= NPIX after claim_k)
    return e - NPIX;
}

// Pass 4: per-root area + fused (max value, min index of max) via one 64-bit
// atomicMax on (float_bits << 32) | ~within_index. Positive float bit patterns
// order like floats; ~idx breaks value ties toward the minimum index.
__global__ void stats_k(const float* __restrict__ x, const int* __restrict__ parent,
                        int* __restrict__ cnt, unsigned long long* __restrict__ best,
                        int cap) {
    int i = blockIdx.x * blockDim.x + threadIdx.x;
    if (i >= NPIX) return;
    float v = x[i];
    if (!(v >= THRESH)) return;
    int cid = compact_id(parent, i);
    if (cid < 0 || cid >= cap) return;           // capacity guard
    atomicAdd(&cnt[cid], 1);
    unsigned int within = (unsigned int)(i & (HW - 1));
    unsigned long long pk =
        ((unsigned long long)__float_as_uint(v) << 32) |
        (unsigned long long)(~within);
    atomicMax(&best[cid], pk);
}

// Pass 5: emit the three FLOAT32 planes (max, row, col) concatenated.
// (Round-2 post-mortem: d_out is float32, not bf16 — the 1032 signature was
// our bf16 row-plane pairs read back as packed float32s.)
__global__ void out_k(const float* __restrict__ x, const int* __restrict__ parent,
                      const int* __restrict__ cnt,
                      const unsigned long long* __restrict__ best,
                      float* __restrict__ o, int cap) {
    int i = blockIdx.x * blockDim.x + threadIdx.x;
    if (i >= NPIX) return;
    float omax = 0.0f, orow = -1.0f, ocol = -1.0f;
    if (x[i] >= THRESH) {
        int cid = compact_id(parent, i);
        if (cid >= 0 && cid < cap && cnt[cid] > 3) {   // area > MIN_AREA
            unsigned long long pk = best[cid];
            unsigned int vb  = (unsigned int)(pk >> 32);
            unsigned int idx = ~((unsigned int)pk);    // within-image flat idx
            omax = __uint_as_float(vb);
            orow = (float)(idx >> 10);                 // idx / W
            ocol = (float)(idx & (WW - 1));            // idx % W
        }
    }
    o[i]            = omax;
    o[i + NPIX]     = orow;
    o[i + 2 * NPIX] = ocol;
}

// ---------------------------------------------------------------------------
extern "C" void kernel_launch(void* const* d_in, const int* in_sizes, int n_in,
                              void* d_out, int out_size, void* d_ws, size_t ws_size,
                              hipStream_t stream) {
    const float* x = (const float*)d_in[0];
    float* o = (float*)d_out;

    // Workspace layout (runtime-sized): parent int32[NPIX] = 32MB, then
    // best u64[cap], cnt int32[cap], counter. 12 B per compact root;
    // ~425k components expected at 6.7% fg density; cap clamped to 2M (24MB).
    char* base = (char*)d_ws;
    int* parent = (int*)base;
    size_t off = (size_t)NPIX * sizeof(int);
    size_t avail = (ws_size > off + 64) ? (ws_size - off - 64) : 0;
    long long capl = (long long)(avail / 12);
    const long long CAP_CLAMP = 2 * 1024 * 1024;
    int cap = (int)((capl > CAP_CLAMP) ? CAP_CLAMP : capl);
    unsigned long long* best = (unsigned long long*)(base + off);     // 8-aligned
    int* cnt     = (int*)(base + off + (size_t)cap * 8);
    int* counter = (int*)(base + off + (size_t)cap * 12);

    const int BLK = 256;
    const int GRD = NPIX / BLK;   // 32768; NPIX >= cap so init covers both

    init_k <<<GRD, BLK, 0, stream>>>(parent, cnt, best, counter, cap);
    union_k<<<GRD, BLK, 0, stream>>>(x, parent);
    claim_k<<<GRD, BLK, 0, stream>>>(x, parent, counter);
    stats_k<<<GRD, BLK, 0, stream>>>(x, parent, cnt, best, cap);
    out_k  <<<GRD, BLK, 0, stream>>>(x, parent, cnt, best, o, cap);
}

// Round 4
// 266.793 us; speedup vs baseline: 6.3076x; 6.3076x over previous
//
#include <hip/hip_runtime.h>
#include <hip/hip_bf16.h>
#include <stdint.h>

#define THRESH 1.5f
constexpr int BB = 8, HH = 1024, WW = 1024;
constexpr int NPIX = BB * HH * WW;   // 8388608 = 2^23
constexpr int HW   = HH * WW;        // 1048576

constexpr int BLK = 256;
constexpr int GRD = NPIX / BLK;            // 32768 (exact)
constexpr int SPB = 48;                    // compact-id slots per block
constexpr int BASE_SLOTS = GRD * SPB;      // 1,572,864
constexpr int OVF_SLOTS  = 16384;          // overflow net (P(use) ~ 1e-15)
constexpr int CAP = BASE_SLOTS + OVF_SLOTS;

// ---------------------------------------------------------------------------
// parent[] encoding:
//   value < NPIX  : union-find pointer (value == self <=> unclaimed root)
//   value >= NPIX : claimed root; compact id = value - NPIX
// ---------------------------------------------------------------------------
__device__ __forceinline__ int find_root(const int* __restrict__ P, int x) {
    int p = P[x];
    while (p != x && p < NPIX) { x = p; p = P[x]; }
    return x;
}

__device__ __forceinline__ void merge(int* P, int a, int b) {
    int ra = find_root(P, a);
    int rb = find_root(P, b);
    while (ra != rb) {
        if (ra < rb) { int t = ra; ra = rb; rb = t; }   // ra > rb
        int old = atomicCAS(&P[ra], ra, rb);            // link larger -> smaller
        if (old == ra) break;
        ra = find_root(P, old);
        rb = find_root(P, rb);
    }
}

// Pass 1: init parent + stats arrays (ws poisoned 0xAA every launch)
__global__ void init_k(int* __restrict__ parent, int* __restrict__ cnt,
                       unsigned long long* __restrict__ best,
                       int* __restrict__ ovf) {
    int i = blockIdx.x * blockDim.x + threadIdx.x;
    if (i < NPIX) parent[i] = i;
    if (i < CAP)  { cnt[i] = 0; best[i] = 0ull; }
    if (i == 0)   *ovf = 0;
}

// Pass 2: union each fg pixel with W, NW, N, NE fg neighbors (covers every
// 8-adjacency edge exactly once; r>0 keeps us inside one image).
__global__ void union_k(const float* __restrict__ x, int* __restrict__ parent) {
    int i = blockIdx.x * blockDim.x + threadIdx.x;
    if (i >= NPIX) return;
    if (!(x[i] >= THRESH)) return;
    int c = i & (WW - 1);
    int r = (i & (HW - 1)) >> 10;
    if (c > 0 && x[i - 1] >= THRESH) merge(parent, i, i - 1);
    if (r > 0) {
        if (x[i - WW] >= THRESH) merge(parent, i, i - WW);
        if (c > 0      && x[i - WW - 1] >= THRESH) merge(parent, i, i - WW - 1);
        if (c < WW - 1 && x[i - WW + 1] >= THRESH) merge(parent, i, i - WW + 1);
    }
}

// Pass 3: path-compress every fg pixel; roots claim DETERMINISTIC per-block
// slots (blockIdx*SPB + LDS-local rank) — no contended global counter.
// (Round-3 post-mortem: ~560k same-address atomicAdds serialized at ~2.6ns
// each = 1.45ms; this pass was 86% of total runtime.)
__global__ void claim_k(const float* __restrict__ x, int* __restrict__ parent,
                        int* __restrict__ ovf) {
    __shared__ int s_cnt;
    if (threadIdx.x == 0) s_cnt = 0;
    __syncthreads();
    int i = blockIdx.x * blockDim.x + threadIdx.x;
    bool isroot = false;
    if (i < NPIX && x[i] >= THRESH) {
        int r = find_root(parent, i);
        if (r == i) isroot = true;
        else        parent[i] = r;
    }
    if (isroot) {
        int rank = atomicAdd(&s_cnt, 1);        // LDS atomic: cheap
        int slot;
        if (rank < SPB) {
            slot = blockIdx.x * SPB + rank;
        } else {                                 // ~never taken
            int o = atomicAdd(ovf, 1);
            slot = BASE_SLOTS + (o < OVF_SLOTS ? o : OVF_SLOTS - 1);
        }
        parent[i] = NPIX + slot;
    }
}

__device__ __forceinline__ int compact_id(const int* __restrict__ P, int i) {
    int e = P[i];                      // direct root ptr or own claim
    if (e < NPIX) e = P[e];            // root's claim (>= NPIX after claim_k)
    return e - NPIX;
}

// Pass 4: per-root area + fused (max value, min index of max) via one 64-bit
// atomicMax on (float_bits << 32) | ~within_index. Positive float bit patterns
// order like floats; ~idx breaks value ties toward the minimum index.
__global__ void stats_k(const float* __restrict__ x, const int* __restrict__ parent,
                        int* __restrict__ cnt, unsigned long long* __restrict__ best) {
    int i = blockIdx.x * blockDim.x + threadIdx.x;
    if (i >= NPIX) return;
    float v = x[i];
    if (!(v >= THRESH)) return;
    int cid = compact_id(parent, i);
    if (cid < 0 || cid >= CAP) return;           // safety guard
    atomicAdd(&cnt[cid], 1);
    unsigned int within = (unsigned int)(i & (HW - 1));
    unsigned long long pk =
        ((unsigned long long)__float_as_uint(v) << 32) |
        (unsigned long long)(~within);
    atomicMax(&best[cid], pk);
}

// Pass 5: emit the three float32 planes (max, row, col) concatenated.
__global__ void out_k(const float* __restrict__ x, const int* __restrict__ parent,
                      const int* __restrict__ cnt,
                      const unsigned long long* __restrict__ best,
                      float* __restrict__ o) {
    int i = blockIdx.x * blockDim.x + threadIdx.x;
    if (i >= NPIX) return;
    float omax = 0.0f, orow = -1.0f, ocol = -1.0f;
    if (x[i] >= THRESH) {
        int cid = compact_id(parent, i);
        if (cid >= 0 && cid < CAP && cnt[cid] > 3) {   // area > MIN_AREA
            unsigned long long pk = best[cid];
            unsigned int vb  = (unsigned int)(pk >> 32);
            unsigned int idx = ~((unsigned int)pk);    // within-image flat idx
            omax = __uint_as_float(vb);
            orow = (float)(idx >> 10);                 // idx / W
            ocol = (float)(idx & (WW - 1));            // idx % W
        }
    }
    o[i]            = omax;
    o[i + NPIX]     = orow;
    o[i + 2 * NPIX] = ocol;
}

// ---------------------------------------------------------------------------
extern "C" void kernel_launch(void* const* d_in, const int* in_sizes, int n_in,
                              void* d_out, int out_size, void* d_ws, size_t ws_size,
                              hipStream_t stream) {
    const float* x = (const float*)d_in[0];
    float* o = (float*)d_out;

    // ws layout: parent i32[NPIX] (33.6MB) | best u64[CAP] (12.7MB) |
    // cnt i32[CAP] (6.4MB) | ovf i32. Total ~52.6MB (< evidenced ws_size).
    char* base = (char*)d_ws;
    int* parent = (int*)base;
    size_t off = (size_t)NPIX * sizeof(int);
    unsigned long long* best = (unsigned long long*)(base + off);
    int* cnt = (int*)(base + off + (size_t)CAP * 8);
    int* ovf = (int*)(base + off + (size_t)CAP * 12);

    init_k <<<GRD, BLK, 0, stream>>>(parent, cnt, best, ovf);
    union_k<<<GRD, BLK, 0, stream>>>(x, parent);
    claim_k<<<GRD, BLK, 0, stream>>>(x, parent, ovf);
    stats_k<<<GRD, BLK, 0, stream>>>(x, parent, cnt, best);
    out_k  <<<GRD, BLK, 0, stream>>>(x, parent, cnt, best, o);
}

// Round 5
// 218.903 us; speedup vs baseline: 7.6875x; 1.2188x over previous
//
#include <hip/hip_runtime.h>
#include <stdint.h>

#define THRESH 1.5f
constexpr int NPIX = 8 * 1024 * 1024;   // 2^23 pixels
constexpr int HW   = 1024 * 1024;       // pixels per image
constexpr int WW   = 1024;              // image width
constexpr int NWORD = NPIX / 32;        // 262144 mask words (32 px each)
constexpr int WPR   = WW / 32;          // 32 words per image row

constexpr int BLK     = 256;
constexpr int GRD_PX4 = NPIX / (BLK * 4);  // 8192 blocks (4 px/thread)
constexpr int GRD_W   = NWORD / BLK;       // 1024 blocks (1 word/thread)

// claim slots: block covers 256 words = 8192 px; E[components] ~ 406 (sigma ~20)
constexpr int SPB        = 640;            // ~11 sigma headroom
constexpr int BASE_SLOTS = GRD_W * SPB;    // 655360
constexpr int OVF_SLOTS  = 16384;          // overflow net
constexpr int CAP        = BASE_SLOTS + OVF_SLOTS;

// ---------------------------------------------------------------------------
// parent[] encoding: < NPIX = union-find pointer (self <=> unclaimed root);
//                   >= NPIX = claimed root, compact id = value - NPIX.
// ---------------------------------------------------------------------------
__device__ __forceinline__ int find_root(const int* __restrict__ P, int x) {
    int p = P[x];
    while (p != x && p < NPIX) { x = p; p = P[x]; }
    return x;
}

__device__ __forceinline__ void merge(int* P, int a, int b) {
    int ra = find_root(P, a);
    int rb = find_root(P, b);
    while (ra != rb) {
        if (ra < rb) { int t = ra; ra = rb; rb = t; }   // ra > rb
        int old = atomicCAS(&P[ra], ra, rb);            // link larger -> smaller
        if (old == ra) break;
        ra = find_root(P, old);
        rb = find_root(P, rb);
    }
}

// Pass 1: read x once (float4), build fg bitmask (1 bit/px), init parent.
__global__ void mask_init_k(const float* __restrict__ x, int* __restrict__ parent,
                            unsigned* __restrict__ mask, int* __restrict__ ovf) {
    __shared__ unsigned s_nib[BLK];
    int t  = threadIdx.x;
    int gt = blockIdx.x * BLK + t;
    int i4 = gt * 4;
    float4 v = *(const float4*)(x + i4);
    unsigned nib = (unsigned)(v.x >= THRESH) | ((unsigned)(v.y >= THRESH) << 1) |
                   ((unsigned)(v.z >= THRESH) << 2) | ((unsigned)(v.w >= THRESH) << 3);
    *(int4*)(parent + i4) = make_int4(i4, i4 + 1, i4 + 2, i4 + 3);
    s_nib[t] = nib;
    __syncthreads();
    if ((t & 7) == 0) {
        unsigned w = 0;
        #pragma unroll
        for (int k = 0; k < 8; k++) w |= s_nib[t + k] << (4 * k);
        mask[gt >> 3] = w;
    }
    if (gt == 0) *ovf = 0;
}

// Pass 2: per-WORD union (32 px/thread). Neighbor tests are bit-ops on the
// mask; only true 8-adjacency edges (~150k total) touch parent.
// (Round-4 post-mortem: per-pixel union_k was latency-bound at 10% HBM, 10%
// VALU — 8.4M threads discovering 90% have nothing to do.)
__global__ void union_k(const unsigned* __restrict__ mask, int* __restrict__ parent) {
    int w = blockIdx.x * BLK + threadIdx.x;
    unsigned cur = mask[w];
    if (!cur) return;
    int r  = (w >> 5) & (WW - 1);   // row within image (words never cross rows)
    int cw = w & (WPR - 1);         // word-column within row
    unsigned prev = (cw > 0) ? mask[w - 1] : 0u;
    unsigned above = 0u, abovePrev = 0u, aboveNext = 0u;
    if (r > 0) {
        above     = mask[w - WPR];
        abovePrev = (cw > 0)       ? mask[w - WPR - 1] : 0u;
        aboveNext = (cw < WPR - 1) ? mask[w - WPR + 1] : 0u;
    }
    int base = w << 5;
    unsigned mW  = cur & ((cur   << 1) | (prev      >> 31));
    unsigned mN  = cur & above;
    unsigned mNW = cur & ((above << 1) | (abovePrev >> 31));
    unsigned mNE = cur & ((above >> 1) | ((aboveNext & 1u) << 31));
    while (mW)  { int b = __ffs(mW)  - 1; mW  &= mW  - 1; merge(parent, base + b, base + b - 1); }
    while (mN)  { int b = __ffs(mN)  - 1; mN  &= mN  - 1; merge(parent, base + b, base + b - WW); }
    while (mNW) { int b = __ffs(mNW) - 1; mNW &= mNW - 1; merge(parent, base + b, base + b - WW - 1); }
    while (mNE) { int b = __ffs(mNE) - 1; mNE &= mNE - 1; merge(parent, base + b, base + b - WW + 1); }
}

// Pass 3: per-word compress + deterministic per-block slot claim; the claimer
// zero-inits its slot's cnt/best (so no dense CAP-wide init pass needed).
__global__ void claim_k(const unsigned* __restrict__ mask, int* __restrict__ parent,
                        int* __restrict__ cnt, unsigned long long* __restrict__ best,
                        int* __restrict__ ovf) {
    __shared__ int s_cnt;
    if (threadIdx.x == 0) s_cnt = 0;
    __syncthreads();
    int w = blockIdx.x * BLK + threadIdx.x;
    unsigned cur = mask[w];
    int base = w << 5;
    while (cur) {
        int b = __ffs(cur) - 1; cur &= cur - 1;
        int p = base + b;
        int root = find_root(parent, p);
        if (root == p) {
            int rank = atomicAdd(&s_cnt, 1);    // LDS atomic: uncontended
            int slot;
            if (rank < SPB) slot = blockIdx.x * SPB + rank;
            else { int o = atomicAdd(ovf, 1); slot = BASE_SLOTS + (o < OVF_SLOTS ? o : OVF_SLOTS - 1); }
            cnt[slot] = 0; best[slot] = 0ull;   // visible to stats_k next kernel
            parent[p] = NPIX + slot;
        } else {
            parent[p] = root;                   // full path compression
        }
    }
}

__device__ __forceinline__ int compact_id(const int* __restrict__ P, int p) {
    int e = P[p];                // direct root ptr or own claim
    if (e < NPIX) e = P[e];      // root's claim (>= NPIX after claim_k)
    return e - NPIX;
}

__device__ __forceinline__ void stat_one(const int* __restrict__ parent,
                                         int* __restrict__ cnt,
                                         unsigned long long* __restrict__ best,
                                         int p, float v) {
    int cid = compact_id(parent, p);
    if (cid < 0 || cid >= CAP) return;
    atomicAdd(&cnt[cid], 1);
    unsigned within = (unsigned)(p & (HW - 1));
    unsigned long long pk =
        ((unsigned long long)__float_as_uint(v) << 32) |
        (unsigned long long)(~within);
    atomicMax(&best[cid], pk);   // fused segment_max + argmin-index-of-max
}

// Pass 4: per-4-px stats, gated on the mask nibble (76% of quads skip x).
__global__ void stats_k(const float* __restrict__ x, const unsigned* __restrict__ mask,
                        const int* __restrict__ parent, int* __restrict__ cnt,
                        unsigned long long* __restrict__ best) {
    int t = blockIdx.x * BLK + threadIdx.x;
    unsigned nib = (mask[t >> 3] >> ((t & 7) * 4)) & 0xFu;
    if (!nib) return;
    int i4 = t * 4;
    float4 v = *(const float4*)(x + i4);
    if (nib & 1u) stat_one(parent, cnt, best, i4,     v.x);
    if (nib & 2u) stat_one(parent, cnt, best, i4 + 1, v.y);
    if (nib & 4u) stat_one(parent, cnt, best, i4 + 2, v.z);
    if (nib & 8u) stat_one(parent, cnt, best, i4 + 3, v.w);
}

__device__ __forceinline__ void lookup_one(const int* __restrict__ parent,
                                           const int* __restrict__ cnt,
                                           const unsigned long long* __restrict__ best,
                                           int p, float& om, float& orow, float& ocol) {
    int cid = compact_id(parent, p);
    if (cid >= 0 && cid < CAP && cnt[cid] > 3) {       // area > MIN_AREA
        unsigned long long pk = best[cid];
        om   = __uint_as_float((unsigned)(pk >> 32));
        unsigned idx = ~((unsigned)pk);                // within-image flat idx
        orow = (float)(idx >> 10);
        ocol = (float)(idx & (WW - 1));
    }
}

// Pass 5: emit float32 planes (max,row,col) with float4 stores; no x read.
__global__ void out_k(const unsigned* __restrict__ mask, const int* __restrict__ parent,
                      const int* __restrict__ cnt,
                      const unsigned long long* __restrict__ best,
                      float* __restrict__ o) {
    int t = blockIdx.x * BLK + threadIdx.x;
    unsigned nib = (mask[t >> 3] >> ((t & 7) * 4)) & 0xFu;
    int i4 = t * 4;
    float4 m  = make_float4(0.f, 0.f, 0.f, 0.f);
    float4 rr = make_float4(-1.f, -1.f, -1.f, -1.f);
    float4 cc = make_float4(-1.f, -1.f, -1.f, -1.f);
    if (nib) {
        if (nib & 1u) lookup_one(parent, cnt, best, i4,     m.x, rr.x, cc.x);
        if (nib & 2u) lookup_one(parent, cnt, best, i4 + 1, m.y, rr.y, cc.y);
        if (nib & 4u) lookup_one(parent, cnt, best, i4 + 2, m.z, rr.z, cc.z);
        if (nib & 8u) lookup_one(parent, cnt, best, i4 + 3, m.w, rr.w, cc.w);
    }
    *(float4*)(o + i4)            = m;
    *(float4*)(o + NPIX + i4)     = rr;
    *(float4*)(o + 2 * NPIX + i4) = cc;
}

// ---------------------------------------------------------------------------
extern "C" void kernel_launch(void* const* d_in, const int* in_sizes, int n_in,
                              void* d_out, int out_size, void* d_ws, size_t ws_size,
                              hipStream_t stream) {
    const float* x = (const float*)d_in[0];
    float* o = (float*)d_out;

    // ws layout: parent i32[NPIX] 33.5MB | best u64[CAP] 5.4MB |
    // cnt i32[CAP] 2.7MB | mask u32[NWORD] 1MB | ovf. Total ~42.7MB.
    char* base = (char*)d_ws;
    int* parent = (int*)base;
    size_t off = (size_t)NPIX * sizeof(int);
    unsigned long long* best = (unsigned long long*)(base + off);
    int* cnt       = (int*)(base + off + (size_t)CAP * 8);
    unsigned* mask = (unsigned*)(base + off + (size_t)CAP * 12);
    int* ovf       = (int*)(base + off + (size_t)CAP * 12 + (size_t)NWORD * 4);

    mask_init_k<<<GRD_PX4, BLK, 0, stream>>>(x, parent, mask, ovf);
    union_k    <<<GRD_W,   BLK, 0, stream>>>(mask, parent);
    claim_k    <<<GRD_W,   BLK, 0, stream>>>(mask, parent, cnt, best, ovf);
    stats_k    <<<GRD_PX4, BLK, 0, stream>>>(x, mask, parent, cnt, best);
    out_k      <<<GRD_PX4, BLK, 0, stream>>>(mask, parent, cnt, best, o);
}